// Round 7
// baseline (3263.342 us; speedup 1.0000x reference)
//
#include <hip/hip_runtime.h>

#define NPIECE 499
#define SEQN 500

typedef __attribute__((ext_vector_type(8))) short bf16x8;
typedef __attribute__((ext_vector_type(4))) float f32x4;
typedef __attribute__((ext_vector_type(2))) float f32x2;

__device__ inline short f2bf(float x) {
    union { float f; unsigned u; } v; v.f = x;
    unsigned r = v.u + 0x7FFFu + ((v.u >> 16) & 1u);   // RNE fp32->bf16
    return (short)(r >> 16);
}

__device__ inline unsigned cvt_pk(float lo, float hi) {  // D.lo=bf16(lo), D.hi=bf16(hi)
    unsigned r;
    asm("v_cvt_pk_bf16_f32 %0, %1, %2" : "=v"(r) : "v"(lo), "v"(hi));
    return r;
}

__device__ inline float xor16(float x) {
    return __int_as_float(__builtin_amdgcn_ds_swizzle(__float_as_int(x), 0x401f));
}

// One block = 32 samples as TWO 16-col groups sharing weight registers.
// 16 blocks x 8 waves. Two barriers serve two evals; streams hide each
// other's latencies.
__global__ void __launch_bounds__(512, 2)
cde_kernel(const float* __restrict__ times,
           const float* __restrict__ ca,  const float* __restrict__ cb,
           const float* __restrict__ c2c, const float* __restrict__ c3d,
           const float* __restrict__ initW, const float* __restrict__ initb,
           const float* __restrict__ W1,  const float* __restrict__ b1,
           const float* __restrict__ W2,  const float* __restrict__ b2,
           const float* __restrict__ linW, const float* __restrict__ linb,
           float* __restrict__ out)
{
    const int tid  = threadIdx.x;
    const int lane = tid & 63;
    const int wv   = tid >> 6;      // wave 0..7
    const int g    = lane >> 4;     // 0..3
    const int col  = lane & 15;     // sample-in-group (B/D col), weight row (A)
    const int g0   = g & 1, g1 = g >> 1;
    const int hi   = lane >> 5;
    const int s0   = blockIdx.x * 32;

    // Activation layout per group: [chunk][physcol][8] bf16,
    // physcol = col ^ (chunk&3); zflat k-slot perm 4*(hid&1)+((hid&7)>>1).
    __shared__ __align__(16) float tl[SEQN];
    __shared__ __align__(16) short zfA[8][16][8],  zfB[8][16][8];
    __shared__ __align__(16) short hfA[16][16][8], hfB[16][16][8];
    __shared__ __align__(16) float dxl[2][3][2][32][4]; // [par][slot][g0][sm32][r]
    __shared__ __align__(16) float zinit[64][32];
    __shared__ __align__(16) float pred[8][32];

    for (int j = tid; j < SEQN; j += 512) tl[j] = times[j];

    // ---------------- weight fragments (bf16, registers, SHARED by groups) ---
    bf16x8 a2[4][4];
    f32x4  b2f[4];
#pragma unroll
    for (int tt = 0; tt < 4; ++tt) {
        const int o = 16 * (4 * wv + tt) + col;
#pragma unroll
        for (int kk = 0; kk < 4; ++kk) {
            bf16x8 f;
#pragma unroll
            for (int e = 0; e < 8; ++e)
                f[e] = f2bf(W2[(32 * kk + 8 * g + e) * 512 + o]);
            a2[tt][kk] = f;
        }
#pragma unroll
        for (int r = 0; r < 4; ++r)
            b2f[tt][r] = b2[16 * (4 * wv + tt) + 4 * g + r];
    }
    bf16x8 a1[2];   // k-perm p(kk,g,e) = 32kk+8g+2(e&3)+(e>>2), cancels z-perm
    f32x4  b1f;
    {
        const int o = 16 * wv + col;
#pragma unroll
        for (int kk = 0; kk < 2; ++kk) {
            bf16x8 f;
#pragma unroll
            for (int e = 0; e < 8; ++e)
                f[e] = f2bf(W1[(32 * kk + 8 * g + 2 * (e & 3) + (e >> 2)) * 128 + o]);
            a1[kk] = f;
        }
#pragma unroll
        for (int r = 0; r < 4; ++r) b1f[r] = b1[16 * wv + 4 * g + r];
    }

    // loop-invariant LDS pointers
    const int colz = col ^ (g & 3);
    const short* zrA0 = &zfA[g][colz][0];      const short* zrB0 = &zfB[g][colz][0];
    const short* zrA1 = &zfA[4 + g][colz][0];  const short* zrB1 = &zfB[4 + g][colz][0];
    const short* hrA0 = &hfA[g][colz][0];      const short* hrB0 = &hfB[g][colz][0];
    const short* hrA1 = &hfA[4 + g][colz][0];  const short* hrB1 = &hfB[4 + g][colz][0];
    const short* hrA2 = &hfA[8 + g][colz][0];  const short* hrB2 = &hfB[8 + g][colz][0];
    const short* hrA3 = &hfA[12 + g][colz][0]; const short* hrB3 = &hfB[12 + g][colz][0];
    short* hwpA = &hfA[2 * wv + g1][col ^ ((2 * wv + g1) & 3)][4 * g0];
    short* hwpB = &hfB[2 * wv + g1][col ^ ((2 * wv + g1) & 3)][4 * g0];
    short* zwpA = &zfA[wv][col ^ (wv & 3)][4 * hi];
    short* zwpB = &zfB[wv][col ^ (wv & 3)][4 * hi];

    __syncthreads();   // tl ready

    // ---------------- z0 = X(t0) @ init_W + init_b ---------------------------
#pragma unroll
    for (int v = 0; v < 4; ++v) {
        const int idx = 4 * tid + v, hid = idx >> 5, sm = idx & 31;
        float z = initb[hid];
#pragma unroll
        for (int c = 0; c < 8; ++c)
            z += ca[((size_t)(s0 + sm)) * (NPIECE * 8) + c] * initW[c * 64 + hid];
        zinit[hid][sm] = z;
        const int ch = hid >> 3, sl = 4 * (hid & 1) + ((hid & 7) >> 1);
        const int pcc = (sm & 15) ^ (ch & 3);
        if (sm < 16) zfA[ch][pcc][sl] = f2bf(z);
        else         zfB[ch][pcc][sl] = f2bf(z);
    }
    // ---------------- dx for step 0 ------------------------------------------
    const int pidx = tid & 255, psm = pidx >> 3, pch2 = pidx & 7;
    const size_t prow = ((size_t)(s0 + psm)) * (NPIECE * 8);
    const bool hih = (tid >= 256);   // waves 4-7: slots 1,2; waves 0-3: slot 0
    {
        float t0n = tl[0], t1n = tl[1], hn = t1n - t0n;
        if (!hih) {
            const size_t off = prow + pch2;     // slot0: piece 0, frac 0
            dxl[0][0][pch2 >> 2][psm][pch2 & 3] = cb[off];
        } else {
            float fr = (t0n + 0.5f * hn) - t0n; // slot1: piece 0
            size_t off = prow + pch2;
            dxl[0][1][pch2 >> 2][psm][pch2 & 3] = cb[off] + (c2c[off] + c3d[off] * fr) * fr;
            float t3 = t0n + hn; int p; float fr2;
            if (t3 > t1n) { p = 1; fr2 = t3 - t1n; } else { p = 0; fr2 = t3 - t0n; }
            off = prow + (size_t)p * 8 + pch2;
            dxl[0][2][pch2 >> 2][psm][pch2 & 3] = cb[off] + (c2c[off] + c3d[off] * fr2) * fr2;
        }
    }
    __syncthreads();

    // RK4 state per group; owner lanes (lane&31)<16 write z
    const bool owner = ((lane & 31) < 16);
    float zreg[2][4], zs[2][4];
#pragma unroll
    for (int grp = 0; grp < 2; ++grp)
#pragma unroll
        for (int tt = 0; tt < 4; ++tt) {
            zs[grp][tt] = 0.f;
            zreg[grp][tt] = zinit[8 * wv + 2 * tt + hi][16 * grp + col];
        }

    for (int i = 0; i < NPIECE; ++i) {
        const float hs = tl[i + 1] - tl[i];
        const float hs_half = 0.5f * hs, hs_sixth = hs * (1.0f / 6.0f);
        const int par = i & 1;

        // register-prefetch next step's spline coefficients
        float pb[2], pcf[2], pd[2], pfr[2];
        const bool pf = (i + 1 < NPIECE);
        if (pf) {
            const int j = i + 1;
            float t0n = tl[j], t1n = tl[j + 1], hn = t1n - t0n;
            if (!hih) {
                pfr[0] = t0n - tl[j - 1];       // slot0: piece j-1
                const size_t off = prow + (size_t)(j - 1) * 8 + pch2;
                pb[0] = cb[off]; pcf[0] = c2c[off]; pd[0] = c3d[off];
            } else {
                pfr[0] = (t0n + 0.5f * hn) - t0n;   // slot1: piece j
                size_t off = prow + (size_t)j * 8 + pch2;
                pb[0] = cb[off]; pcf[0] = c2c[off]; pd[0] = c3d[off];
                float t3 = t0n + hn; int p;         // slot2
                if (j < NPIECE - 1 && t3 > t1n) { p = j + 1; pfr[1] = t3 - t1n; }
                else                            { p = j;     pfr[1] = t3 - t0n; }
                off = prow + (size_t)p * 8 + pch2;
                pb[1] = cb[off]; pcf[1] = c2c[off]; pd[1] = c3d[off];
            }
        }

#pragma unroll
        for (int st = 0; st < 4; ++st) {
            const int dsel = (st == 0) ? 0 : ((st == 3) ? 2 : 1);
            __syncthreads();   // barrier A: z (both groups) + dxl[par] ready

            // dx reads (hidden under L1+L2 phases)
            const f32x4 ddA = *(const f32x4*)&dxl[par][dsel][g0][col][0];
            const f32x4 ddB = *(const f32x4*)&dxl[par][dsel][g0][16 + col][0];
            if (st == 3 && pf) {
                if (!hih)
                    dxl[par ^ 1][0][pch2 >> 2][psm][pch2 & 3] =
                        pb[0] + (pcf[0] + pd[0] * pfr[0]) * pfr[0];
                else {
                    dxl[par ^ 1][1][pch2 >> 2][psm][pch2 & 3] =
                        pb[0] + (pcf[0] + pd[0] * pfr[0]) * pfr[0];
                    dxl[par ^ 1][2][pch2 >> 2][psm][pch2 & 3] =
                        pb[1] + (pcf[1] + pd[1] * pfr[1]) * pfr[1];
                }
            }

            // ---- layer1 both groups: h = relu(z @ W1 + b1) ----
            bf16x8 bzA0 = *(const bf16x8*)zrA0, bzA1 = *(const bf16x8*)zrA1;
            bf16x8 bzB0 = *(const bf16x8*)zrB0, bzB1 = *(const bf16x8*)zrB1;
            f32x4 haA, haB;
            haA = __builtin_amdgcn_mfma_f32_16x16x32_bf16(a1[0], bzA0, b1f, 0, 0, 0);
            haB = __builtin_amdgcn_mfma_f32_16x16x32_bf16(a1[0], bzB0, b1f, 0, 0, 0);
            haA = __builtin_amdgcn_mfma_f32_16x16x32_bf16(a1[1], bzA1, haA, 0, 0, 0);
            haB = __builtin_amdgcn_mfma_f32_16x16x32_bf16(a1[1], bzB1, haB, 0, 0, 0);
            int2 hwA, hwB;
            hwA.x = (int)cvt_pk(fmaxf(haA[0], 0.f), fmaxf(haA[1], 0.f));
            hwA.y = (int)cvt_pk(fmaxf(haA[2], 0.f), fmaxf(haA[3], 0.f));
            hwB.x = (int)cvt_pk(fmaxf(haB[0], 0.f), fmaxf(haB[1], 0.f));
            hwB.y = (int)cvt_pk(fmaxf(haB[2], 0.f), fmaxf(haB[3], 0.f));
            *(int2*)hwpA = hwA;
            *(int2*)hwpB = hwB;
            __syncthreads();   // barrier B: h (both groups) ready

            // ---- layer2 both groups ----
            bf16x8 bhA0 = *(const bf16x8*)hrA0, bhA1 = *(const bf16x8*)hrA1;
            bf16x8 bhA2 = *(const bf16x8*)hrA2, bhA3 = *(const bf16x8*)hrA3;
            bf16x8 bhB0 = *(const bf16x8*)hrB0, bhB1 = *(const bf16x8*)hrB1;
            bf16x8 bhB2 = *(const bf16x8*)hrB2, bhB3 = *(const bf16x8*)hrB3;
            f32x4 ccA[4], ccB[4];
#pragma unroll
            for (int tt = 0; tt < 4; ++tt)
                ccA[tt] = __builtin_amdgcn_mfma_f32_16x16x32_bf16(a2[tt][0], bhA0, b2f[tt], 0, 0, 0);
#pragma unroll
            for (int tt = 0; tt < 4; ++tt)
                ccB[tt] = __builtin_amdgcn_mfma_f32_16x16x32_bf16(a2[tt][0], bhB0, b2f[tt], 0, 0, 0);
#pragma unroll
            for (int tt = 0; tt < 4; ++tt)
                ccA[tt] = __builtin_amdgcn_mfma_f32_16x16x32_bf16(a2[tt][1], bhA1, ccA[tt], 0, 0, 0);
#pragma unroll
            for (int tt = 0; tt < 4; ++tt)
                ccB[tt] = __builtin_amdgcn_mfma_f32_16x16x32_bf16(a2[tt][1], bhB1, ccB[tt], 0, 0, 0);
#pragma unroll
            for (int tt = 0; tt < 4; ++tt)
                ccA[tt] = __builtin_amdgcn_mfma_f32_16x16x32_bf16(a2[tt][2], bhA2, ccA[tt], 0, 0, 0);
#pragma unroll
            for (int tt = 0; tt < 4; ++tt)
                ccB[tt] = __builtin_amdgcn_mfma_f32_16x16x32_bf16(a2[tt][2], bhB2, ccB[tt], 0, 0, 0);
#pragma unroll
            for (int tt = 0; tt < 4; ++tt)
                ccA[tt] = __builtin_amdgcn_mfma_f32_16x16x32_bf16(a2[tt][3], bhA3, ccA[tt], 0, 0, 0);
#pragma unroll
            for (int tt = 0; tt < 4; ++tt)
                ccB[tt] = __builtin_amdgcn_mfma_f32_16x16x32_bf16(a2[tt][3], bhB3, ccB[tt], 0, 0, 0);

            // ---- tanh + contraction + RK4, group A then B (B's MFMAs drain under A) ----
#pragma unroll
            for (int grp = 0; grp < 2; ++grp) {
                const f32x4* cc = grp ? ccB : ccA;
                const f32x4  dd = grp ? ddB : ddA;
                float pt[4];
#pragma unroll
                for (int tt = 0; tt < 4; ++tt) {
                    f32x2 s2 = {0.f, 0.f};
#pragma unroll
                    for (int r2 = 0; r2 < 2; ++r2) {
                        f32x2 x = { cc[tt][2 * r2], cc[tt][2 * r2 + 1] };
                        f32x2 a = x * 2.8853900817779268f;
                        f32x2 e = { __builtin_amdgcn_exp2f(a.x),
                                    __builtin_amdgcn_exp2f(a.y) };
                        e = e + 1.0f;
                        f32x2 rr = { __builtin_amdgcn_rcpf(e.x),
                                     __builtin_amdgcn_rcpf(e.y) };
                        f32x2 th = (-2.0f) * rr + 1.0f;
                        f32x2 d2 = { dd[2 * r2], dd[2 * r2 + 1] };
                        s2 = th * d2 + s2;
                    }
                    pt[tt] = s2.x + s2.y;
                }
#pragma unroll
                for (int tt = 0; tt < 4; ++tt)
                    pt[tt] += xor16(pt[tt]);

                if (owner) {
                    float zw[4];
#pragma unroll
                    for (int tt = 0; tt < 4; ++tt) {
                        const float k = pt[tt];
                        float zst;
                        if (st == 0)      { zs[grp][tt] = k;                         zst = fmaf(hs_half, k, zreg[grp][tt]); }
                        else if (st == 1) { zs[grp][tt] = fmaf(2.f, k, zs[grp][tt]); zst = fmaf(hs_half, k, zreg[grp][tt]); }
                        else if (st == 2) { zs[grp][tt] = fmaf(2.f, k, zs[grp][tt]); zst = fmaf(hs, k, zreg[grp][tt]); }
                        else              { zs[grp][tt] += k;                        zst = fmaf(hs_sixth, zs[grp][tt], zreg[grp][tt]);
                                            zreg[grp][tt] = zst; }
                        zw[tt] = zst;
                    }
                    int2 wd;
                    wd.x = (int)cvt_pk(zw[0], zw[1]);
                    wd.y = (int)cvt_pk(zw[2], zw[3]);
                    if (grp == 0) *(int2*)zwpA = wd;
                    else          *(int2*)zwpB = wd;
                }
            }
        }
    }

    // ---------------- readout: sigmoid(z @ lin_W + lin_b) --------------------
    float pacc[2] = {0.f, 0.f};
#pragma unroll
    for (int grp = 0; grp < 2; ++grp) {
#pragma unroll
        for (int tt = 0; tt < 4; ++tt)
            pacc[grp] += zreg[grp][tt] * linW[8 * wv + 2 * tt + hi];
        pacc[grp] += __shfl_xor(pacc[grp], 32);
    }
    if (lane < 16) { pred[wv][col] = pacc[0]; pred[wv][16 + col] = pacc[1]; }
    __syncthreads();
    if (tid < 32) {
        float a = linb[0];
#pragma unroll
        for (int w = 0; w < 8; ++w) a += pred[w][tid];
        out[s0 + tid] = 1.0f / (1.0f + __expf(-a));
    }
}

extern "C" void kernel_launch(void* const* d_in, const int* in_sizes, int n_in,
                              void* d_out, int out_size, void* d_ws, size_t ws_size,
                              hipStream_t stream) {
    (void)in_sizes; (void)n_in; (void)d_ws; (void)ws_size; (void)out_size;
    const float* times = (const float*)d_in[0];
    const float* ca    = (const float*)d_in[1];
    const float* cb    = (const float*)d_in[2];
    const float* c2c   = (const float*)d_in[3];
    const float* c3d   = (const float*)d_in[4];
    const float* initW = (const float*)d_in[5];
    const float* initb = (const float*)d_in[6];
    const float* W1    = (const float*)d_in[7];
    const float* b1    = (const float*)d_in[8];
    const float* W2    = (const float*)d_in[9];
    const float* b2    = (const float*)d_in[10];
    const float* linW  = (const float*)d_in[11];
    const float* linb  = (const float*)d_in[12];
    cde_kernel<<<16, 512, 0, stream>>>(times, ca, cb, c2c, c3d, initW, initb,
                                       W1, b1, W2, b2, linW, linb, (float*)d_out);
}

// Round 8
// 2409.736 us; speedup vs baseline: 1.3542x; 1.3542x over previous
//
#include <hip/hip_runtime.h>

#define NPIECE 499
#define SEQN 500

typedef __attribute__((ext_vector_type(8))) short bf16x8;
typedef __attribute__((ext_vector_type(4))) float f32x4;
typedef __attribute__((ext_vector_type(2))) float f32x2;

__device__ inline short f2bf(float x) {
    union { float f; unsigned u; } v; v.f = x;
    unsigned r = v.u + 0x7FFFu + ((v.u >> 16) & 1u);   // RNE fp32->bf16
    return (short)(r >> 16);
}

__device__ inline unsigned cvt_pk(float lo, float hi) {  // D.lo=bf16(lo), D.hi=bf16(hi)
    unsigned r;
    asm("v_cvt_pk_bf16_f32 %0, %1, %2" : "=v"(r) : "v"(lo), "v"(hi));
    return r;
}

__device__ inline float xor16(float x) {
    return __int_as_float(__builtin_amdgcn_ds_swizzle(__float_as_int(x), 0x401f));
}

// One block = 16 samples, 8 waves, 32 blocks. ONE barrier per MLP eval:
// every wave computes full layer-1 redundantly; MFMA k-perms make L1's
// D-fragments directly the L2 B-operand fragments (no LDS h round-trip).
// launch_bounds(512,1) -> 256-VGPR cap (R3's spill fixed); biases in LDS.
__global__ void __launch_bounds__(512, 1)
cde_kernel(const float* __restrict__ times,
           const float* __restrict__ ca,  const float* __restrict__ cb,
           const float* __restrict__ c2c, const float* __restrict__ c3d,
           const float* __restrict__ initW, const float* __restrict__ initb,
           const float* __restrict__ W1,  const float* __restrict__ b1,
           const float* __restrict__ W2,  const float* __restrict__ b2,
           const float* __restrict__ linW, const float* __restrict__ linb,
           float* __restrict__ out)
{
    const int tid  = threadIdx.x;
    const int lane = tid & 63;
    const int wv   = tid >> 6;      // wave 0..7
    const int g    = lane >> 4;     // 0..3
    const int col  = lane & 15;     // sample (B/D col), weight row (A)
    const int g0   = g & 1;
    const int hi   = lane >> 5;
    const int s0   = blockIdx.x * 16;

    __shared__ __align__(16) float tl[SEQN];
    __shared__ __align__(16) short zflat[2][8][16][8];  // stage-parity dbuf, XOR cols
    __shared__ __align__(16) float dxl[2][3][2][16][4]; // [par][slot][g0][sm][r]
    __shared__ __align__(16) float zinit[64][16];
    __shared__ __align__(16) float b1l[128];
    __shared__ __align__(16) float b2l[512];
    __shared__ __align__(16) float pred[8][16];

    for (int j = tid; j < SEQN; j += 512) tl[j] = times[j];
    if (tid < 128) b1l[tid] = b1[tid];
    b2l[tid] = b2[tid];

    // ---- A2 fragments: k-perm q(c,g,e) = 32c + 16(e>>2) + 4g + (e&3) -------
    bf16x8 a2[4][4];
#pragma unroll
    for (int tt = 0; tt < 4; ++tt) {
        const int o = 16 * (4 * wv + tt) + col;
#pragma unroll
        for (int c = 0; c < 4; ++c) {
            bf16x8 f;
#pragma unroll
            for (int e = 0; e < 8; ++e) {
                const int q = 32 * c + 16 * (e >> 2) + 4 * g + (e & 3);
                f[e] = f2bf(W2[q * 512 + o]);
            }
            a2[tt][c] = f;
        }
    }
    // ---- A1 fragments (full L1): k-perm p(c,g,e) = 32c + 8g + 2(e&3)+(e>>2)
    bf16x8 a1[8][2];
#pragma unroll
    for (int t = 0; t < 8; ++t) {
#pragma unroll
        for (int c = 0; c < 2; ++c) {
            bf16x8 f;
#pragma unroll
            for (int e = 0; e < 8; ++e) {
                const int p = 32 * c + 8 * g + 2 * (e & 3) + (e >> 2);
                f[e] = f2bf(W1[p * 128 + 16 * t + col]);
            }
            a1[t][c] = f;
        }
    }

    // loop-invariant LDS pointers (zflat[ch][truecol ^ (ch&3)][slot])
    const int colz = col ^ (g & 3);
    const short* zr00 = &zflat[0][g][colz][0];
    const short* zr01 = &zflat[0][4 + g][colz][0];
    const short* zr10 = &zflat[1][g][colz][0];
    const short* zr11 = &zflat[1][4 + g][colz][0];
    short* zwp0 = &zflat[0][wv][col ^ (wv & 3)][4 * hi];
    short* zwp1 = &zflat[1][wv][col ^ (wv & 3)][4 * hi];

    __syncthreads();   // tl, biases ready

    // ---- z0 = X(t0) @ init_W + init_b; slot perm sl = 4(hid&1)+((hid&7)>>1)
#pragma unroll
    for (int v = 0; v < 2; ++v) {
        const int idx = tid * 2 + v, hid = idx >> 4, sm = idx & 15;
        float z = initb[hid];
#pragma unroll
        for (int c = 0; c < 8; ++c)
            z += ca[((size_t)(s0 + sm)) * (NPIECE * 8) + c] * initW[c * 64 + hid];
        zinit[hid][sm] = z;
        const int ch = hid >> 3;
        zflat[0][ch][sm ^ (ch & 3)][4 * (hid & 1) + ((hid & 7) >> 1)] = f2bf(z);
    }
    // ---- dx for step 0 -------------------------------------------------------
    const int pslot = tid >> 7, prr = tid & 127, psm = prr >> 3, pch = prr & 7;
    const size_t prow = ((size_t)(s0 + psm)) * (NPIECE * 8);
    if (tid < 384) {
        float t0n = tl[0], t1n = tl[1], hn = t1n - t0n; int p; float fr;
        if (pslot == 0)      { p = 0; fr = 0.0f; }
        else if (pslot == 1) { p = 0; fr = (t0n + 0.5f * hn) - t0n; }
        else { float t3 = t0n + hn;
               if (t3 > t1n) { p = 1; fr = t3 - t1n; } else { p = 0; fr = t3 - t0n; } }
        const size_t off = prow + (size_t)p * 8 + pch;
        dxl[0][pslot][pch >> 2][psm][pch & 3] = cb[off] + (c2c[off] + c3d[off] * fr) * fr;
    }
    __syncthreads();

    // RK4 state: all lanes track z[8wv+2tt+hi][col]; (lane&16)==0 lanes write
    float zreg[4], zs[4];
#pragma unroll
    for (int tt = 0; tt < 4; ++tt) {
        zs[tt] = 0.f;
        zreg[tt] = zinit[8 * wv + 2 * tt + hi][col];
    }

    for (int i = 0; i < NPIECE; ++i) {
        const float hs = tl[i + 1] - tl[i];
        const float hs_half = 0.5f * hs, hs_sixth = hs * (1.0f / 6.0f);
        const int par = i & 1;

        // register-prefetch next step's spline coefficients
        float pb = 0.f, pc = 0.f, pd = 0.f, pfr = 0.f;
        const bool pf = (i + 1 < NPIECE) && (tid < 384);
        if (pf) {
            const int j = i + 1;
            float t0n = tl[j], t1n = tl[j + 1], hn = t1n - t0n; int p; float fr;
            if (pslot == 0)      { p = j - 1; fr = t0n - tl[j - 1]; }
            else if (pslot == 1) { p = j; fr = (t0n + 0.5f * hn) - t0n; }
            else { float t3 = t0n + hn;
                   if (j < NPIECE - 1 && t3 > t1n) { p = j + 1; fr = t3 - t1n; }
                   else                            { p = j;     fr = t3 - t0n; } }
            const size_t off = prow + (size_t)p * 8 + pch;
            pb = cb[off]; pc = c2c[off]; pd = c3d[off]; pfr = fr;
        }

#pragma unroll
        for (int st = 0; st < 4; ++st) {
            const int rb = st & 1;
            const int dsel = (st == 0) ? 0 : ((st == 3) ? 2 : 1);
            __syncthreads();   // the ONLY barrier per eval

            // issue all LDS reads up front
            bf16x8 bz0 = *(const bf16x8*)(rb ? zr10 : zr00);
            bf16x8 bz1 = *(const bf16x8*)(rb ? zr11 : zr01);
            const f32x4 dd = *(const f32x4*)&dxl[par][dsel][g0][col][0];
            f32x4 b2i[4];
#pragma unroll
            for (int tt = 0; tt < 4; ++tt)
                b2i[tt] = *(const f32x4*)&b2l[16 * (4 * wv + tt) + 4 * g];
            if (st == 3 && pf)
                dxl[par ^ 1][pslot][pch >> 2][psm][pch & 3] = pb + (pc + pd * pfr) * pfr;

            // ---- layer1 (full, redundant) in pairs; pack D->B via perms ----
            union { bf16x8 v; unsigned u[4]; } bh[4];
#pragma unroll
            for (int c = 0; c < 4; ++c) {
                f32x4 b1a = *(const f32x4*)&b1l[16 * (2 * c) + 4 * g];
                f32x4 b1b = *(const f32x4*)&b1l[16 * (2 * c + 1) + 4 * g];
                f32x4 h0 = __builtin_amdgcn_mfma_f32_16x16x32_bf16(a1[2 * c][0], bz0, b1a, 0, 0, 0);
                f32x4 h1 = __builtin_amdgcn_mfma_f32_16x16x32_bf16(a1[2 * c + 1][0], bz0, b1b, 0, 0, 0);
                h0 = __builtin_amdgcn_mfma_f32_16x16x32_bf16(a1[2 * c][1], bz1, h0, 0, 0, 0);
                h1 = __builtin_amdgcn_mfma_f32_16x16x32_bf16(a1[2 * c + 1][1], bz1, h1, 0, 0, 0);
                bh[c].u[0] = cvt_pk(fmaxf(h0[0], 0.f), fmaxf(h0[1], 0.f));
                bh[c].u[1] = cvt_pk(fmaxf(h0[2], 0.f), fmaxf(h0[3], 0.f));
                bh[c].u[2] = cvt_pk(fmaxf(h1[0], 0.f), fmaxf(h1[1], 0.f));
                bh[c].u[3] = cvt_pk(fmaxf(h1[2], 0.f), fmaxf(h1[3], 0.f));
            }

            // ---- layer2: 4 tiles x 4 chunks (bias via C-init) ----
            f32x4 cc[4];
#pragma unroll
            for (int tt = 0; tt < 4; ++tt)
                cc[tt] = __builtin_amdgcn_mfma_f32_16x16x32_bf16(a2[tt][0], bh[0].v, b2i[tt], 0, 0, 0);
#pragma unroll
            for (int c = 1; c < 4; ++c)
#pragma unroll
                for (int tt = 0; tt < 4; ++tt)
                    cc[tt] = __builtin_amdgcn_mfma_f32_16x16x32_bf16(a2[tt][c], bh[c].v, cc[tt], 0, 0, 0);

            // ---- tanh + contraction ----
            float pt[4];
#pragma unroll
            for (int tt = 0; tt < 4; ++tt) {
                f32x2 s2 = {0.f, 0.f};
#pragma unroll
                for (int r2 = 0; r2 < 2; ++r2) {
                    f32x2 x = { cc[tt][2 * r2], cc[tt][2 * r2 + 1] };
                    f32x2 a = x * 2.8853900817779268f;
                    f32x2 e = { __builtin_amdgcn_exp2f(a.x),
                                __builtin_amdgcn_exp2f(a.y) };
                    e = e + 1.0f;
                    f32x2 rr = { __builtin_amdgcn_rcpf(e.x),
                                 __builtin_amdgcn_rcpf(e.y) };
                    f32x2 th = (-2.0f) * rr + 1.0f;
                    f32x2 d2 = { dd[2 * r2], dd[2 * r2 + 1] };
                    s2 = th * d2 + s2;
                }
                pt[tt] = s2.x + s2.y;
            }
#pragma unroll
            for (int tt = 0; tt < 4; ++tt)
                pt[tt] += xor16(pt[tt]);   // sum over g0

            // ---- RK4 update (all lanes track; (lane&16)==0 write packed) ----
            float zw[4];
#pragma unroll
            for (int tt = 0; tt < 4; ++tt) {
                const float k = pt[tt];
                float zst;
                if (st == 0)      { zs[tt] = k;                    zst = fmaf(hs_half, k, zreg[tt]); }
                else if (st == 1) { zs[tt] = fmaf(2.f, k, zs[tt]); zst = fmaf(hs_half, k, zreg[tt]); }
                else if (st == 2) { zs[tt] = fmaf(2.f, k, zs[tt]); zst = fmaf(hs, k, zreg[tt]); }
                else              { zs[tt] += k;                   zst = fmaf(hs_sixth, zs[tt], zreg[tt]);
                                    zreg[tt] = zst; }
                zw[tt] = zst;
            }
            if (!(lane & 16)) {
                int2 wd;
                wd.x = (int)cvt_pk(zw[0], zw[1]);
                wd.y = (int)cvt_pk(zw[2], zw[3]);
                *(int2*)(rb ? zwp0 : zwp1) = wd;   // write buffer rb^1
            }
        }
    }

    // ---------------- readout: sigmoid(z @ lin_W + lin_b) --------------------
    float p = 0.f;
#pragma unroll
    for (int tt = 0; tt < 4; ++tt) p += zreg[tt] * linW[8 * wv + 2 * tt + hi];
    p += __shfl_xor(p, 32);
    if (lane < 16) pred[wv][col] = p;
    __syncthreads();
    if (tid < 16) {
        float a = linb[0];
#pragma unroll
        for (int w = 0; w < 8; ++w) a += pred[w][tid];
        out[s0 + tid] = 1.0f / (1.0f + __expf(-a));
    }
}

extern "C" void kernel_launch(void* const* d_in, const int* in_sizes, int n_in,
                              void* d_out, int out_size, void* d_ws, size_t ws_size,
                              hipStream_t stream) {
    (void)in_sizes; (void)n_in; (void)d_ws; (void)ws_size; (void)out_size;
    const float* times = (const float*)d_in[0];
    const float* ca    = (const float*)d_in[1];
    const float* cb    = (const float*)d_in[2];
    const float* c2c   = (const float*)d_in[3];
    const float* c3d   = (const float*)d_in[4];
    const float* initW = (const float*)d_in[5];
    const float* initb = (const float*)d_in[6];
    const float* W1    = (const float*)d_in[7];
    const float* b1    = (const float*)d_in[8];
    const float* W2    = (const float*)d_in[9];
    const float* b2    = (const float*)d_in[10];
    const float* linW  = (const float*)d_in[11];
    const float* linb  = (const float*)d_in[12];
    cde_kernel<<<32, 512, 0, stream>>>(times, ca, cb, c2c, c3d, initW, initb,
                                       W1, b1, W2, b2, linW, linb, (float*)d_out);
}

// Round 9
// 2405.931 us; speedup vs baseline: 1.3564x; 1.0016x over previous
//
#include <hip/hip_runtime.h>

#define NPIECE 499
#define SEQN 500

typedef __attribute__((ext_vector_type(8))) short bf16x8;
typedef __attribute__((ext_vector_type(4))) float f32x4;
typedef __attribute__((ext_vector_type(2))) float f32x2;

__device__ inline short f2bf(float x) {
    union { float f; unsigned u; } v; v.f = x;
    unsigned r = v.u + 0x7FFFu + ((v.u >> 16) & 1u);   // RNE fp32->bf16
    return (short)(r >> 16);
}

__device__ inline unsigned cvt_pk(float lo, float hi) {  // D.lo=bf16(lo), D.hi=bf16(hi)
    unsigned r;
    asm("v_cvt_pk_bf16_f32 %0, %1, %2" : "=v"(r) : "v"(lo), "v"(hi));
    return r;
}

__device__ inline float xor16(float x) {
    return __int_as_float(__builtin_amdgcn_ds_swizzle(__float_as_int(x), 0x401f));
}

// One block = 16 samples, 8 waves, 32 blocks. ONE barrier per MLP eval:
// every wave computes full layer-1 redundantly; MFMA k-perms make L1's
// D-fragments directly the L2 B-operand fragments (no LDS h round-trip).
// amdgpu_waves_per_eu(2,2): 2 waves/SIMD -> 256-reg/wave budget (fixes the
// 128-arch-VGPR cap that spilled R3/R7; occupancy unchanged at 1 block/CU).
__global__ void
__attribute__((amdgpu_flat_work_group_size(512, 512), amdgpu_waves_per_eu(2, 2)))
cde_kernel(const float* __restrict__ times,
           const float* __restrict__ ca,  const float* __restrict__ cb,
           const float* __restrict__ c2c, const float* __restrict__ c3d,
           const float* __restrict__ initW, const float* __restrict__ initb,
           const float* __restrict__ W1,  const float* __restrict__ b1,
           const float* __restrict__ W2,  const float* __restrict__ b2,
           const float* __restrict__ linW, const float* __restrict__ linb,
           float* __restrict__ out)
{
    const int tid  = threadIdx.x;
    const int lane = tid & 63;
    const int wv   = tid >> 6;      // wave 0..7
    const int g    = lane >> 4;     // 0..3
    const int col  = lane & 15;     // sample (B/D col), weight row (A)
    const int g0   = g & 1;
    const int hi   = lane >> 5;
    const int s0   = blockIdx.x * 16;

    __shared__ __align__(16) float tl[SEQN];
    __shared__ __align__(16) short zflat[2][8][16][8];  // stage-parity dbuf, XOR cols
    __shared__ __align__(16) float dxl[2][3][2][16][4]; // [par][slot][g0][sm][r]
    __shared__ __align__(16) float zinit[64][16];
    __shared__ __align__(16) float b1l[128];
    __shared__ __align__(16) float b2l[512];
    __shared__ __align__(16) float pred[8][16];

    for (int j = tid; j < SEQN; j += 512) tl[j] = times[j];
    if (tid < 128) b1l[tid] = b1[tid];
    b2l[tid] = b2[tid];

    // ---- A2 fragments: k-perm q(c,g,e) = 32c + 16(e>>2) + 4g + (e&3) -------
    bf16x8 a2[4][4];
#pragma unroll
    for (int tt = 0; tt < 4; ++tt) {
        const int o = 16 * (4 * wv + tt) + col;
#pragma unroll
        for (int c = 0; c < 4; ++c) {
            bf16x8 f;
#pragma unroll
            for (int e = 0; e < 8; ++e) {
                const int q = 32 * c + 16 * (e >> 2) + 4 * g + (e & 3);
                f[e] = f2bf(W2[q * 512 + o]);
            }
            a2[tt][c] = f;
        }
    }
    // ---- A1 fragments (full L1): k-perm p(c,g,e) = 32c + 8g + 2(e&3)+(e>>2)
    bf16x8 a1[8][2];
#pragma unroll
    for (int t = 0; t < 8; ++t) {
#pragma unroll
        for (int c = 0; c < 2; ++c) {
            bf16x8 f;
#pragma unroll
            for (int e = 0; e < 8; ++e) {
                const int p = 32 * c + 8 * g + 2 * (e & 3) + (e >> 2);
                f[e] = f2bf(W1[p * 128 + 16 * t + col]);
            }
            a1[t][c] = f;
        }
    }

    // loop-invariant LDS pointers (zflat[ch][truecol ^ (ch&3)][slot])
    const int colz = col ^ (g & 3);
    const short* zr00 = &zflat[0][g][colz][0];
    const short* zr01 = &zflat[0][4 + g][colz][0];
    const short* zr10 = &zflat[1][g][colz][0];
    const short* zr11 = &zflat[1][4 + g][colz][0];
    short* zwp0 = &zflat[0][wv][col ^ (wv & 3)][4 * hi];
    short* zwp1 = &zflat[1][wv][col ^ (wv & 3)][4 * hi];

    __syncthreads();   // tl, biases ready

    // ---- z0 = X(t0) @ init_W + init_b; slot perm sl = 4(hid&1)+((hid&7)>>1)
#pragma unroll
    for (int v = 0; v < 2; ++v) {
        const int idx = tid * 2 + v, hid = idx >> 4, sm = idx & 15;
        float z = initb[hid];
#pragma unroll
        for (int c = 0; c < 8; ++c)
            z += ca[((size_t)(s0 + sm)) * (NPIECE * 8) + c] * initW[c * 64 + hid];
        zinit[hid][sm] = z;
        const int ch = hid >> 3;
        zflat[0][ch][sm ^ (ch & 3)][4 * (hid & 1) + ((hid & 7) >> 1)] = f2bf(z);
    }
    // ---- dx for step 0 -------------------------------------------------------
    const int pslot = tid >> 7, prr = tid & 127, psm = prr >> 3, pch = prr & 7;
    const size_t prow = ((size_t)(s0 + psm)) * (NPIECE * 8);
    if (tid < 384) {
        float t0n = tl[0], t1n = tl[1], hn = t1n - t0n; int p; float fr;
        if (pslot == 0)      { p = 0; fr = 0.0f; }
        else if (pslot == 1) { p = 0; fr = (t0n + 0.5f * hn) - t0n; }
        else { float t3 = t0n + hn;
               if (t3 > t1n) { p = 1; fr = t3 - t1n; } else { p = 0; fr = t3 - t0n; } }
        const size_t off = prow + (size_t)p * 8 + pch;
        dxl[0][pslot][pch >> 2][psm][pch & 3] = cb[off] + (c2c[off] + c3d[off] * fr) * fr;
    }
    __syncthreads();

    // RK4 state: all lanes track z[8wv+2tt+hi][col]; (lane&16)==0 lanes write
    float zreg[4], zs[4];
#pragma unroll
    for (int tt = 0; tt < 4; ++tt) {
        zs[tt] = 0.f;
        zreg[tt] = zinit[8 * wv + 2 * tt + hi][col];
    }

    for (int i = 0; i < NPIECE; ++i) {
        const float hs = tl[i + 1] - tl[i];
        const float hs_half = 0.5f * hs, hs_sixth = hs * (1.0f / 6.0f);
        const int par = i & 1;

        // register-prefetch next step's spline coefficients
        float pb = 0.f, pc = 0.f, pd = 0.f, pfr = 0.f;
        const bool pf = (i + 1 < NPIECE) && (tid < 384);
        if (pf) {
            const int j = i + 1;
            float t0n = tl[j], t1n = tl[j + 1], hn = t1n - t0n; int p; float fr;
            if (pslot == 0)      { p = j - 1; fr = t0n - tl[j - 1]; }
            else if (pslot == 1) { p = j; fr = (t0n + 0.5f * hn) - t0n; }
            else { float t3 = t0n + hn;
                   if (j < NPIECE - 1 && t3 > t1n) { p = j + 1; fr = t3 - t1n; }
                   else                            { p = j;     fr = t3 - t0n; } }
            const size_t off = prow + (size_t)p * 8 + pch;
            pb = cb[off]; pc = c2c[off]; pd = c3d[off]; pfr = fr;
        }

#pragma unroll
        for (int st = 0; st < 4; ++st) {
            const int rb = st & 1;
            const int dsel = (st == 0) ? 0 : ((st == 3) ? 2 : 1);
            __syncthreads();   // the ONLY barrier per eval

            // issue all LDS reads up front
            bf16x8 bz0 = *(const bf16x8*)(rb ? zr10 : zr00);
            bf16x8 bz1 = *(const bf16x8*)(rb ? zr11 : zr01);
            const f32x4 dd = *(const f32x4*)&dxl[par][dsel][g0][col][0];
            f32x4 b2i[4];
#pragma unroll
            for (int tt = 0; tt < 4; ++tt)
                b2i[tt] = *(const f32x4*)&b2l[16 * (4 * wv + tt) + 4 * g];
            if (st == 3 && pf)
                dxl[par ^ 1][pslot][pch >> 2][psm][pch & 3] = pb + (pc + pd * pfr) * pfr;

            // ---- layer1 (full, redundant) in pairs; pack D->B via perms ----
            union { bf16x8 v; unsigned u[4]; } bh[4];
#pragma unroll
            for (int c = 0; c < 4; ++c) {
                f32x4 b1a = *(const f32x4*)&b1l[16 * (2 * c) + 4 * g];
                f32x4 b1b = *(const f32x4*)&b1l[16 * (2 * c + 1) + 4 * g];
                f32x4 h0 = __builtin_amdgcn_mfma_f32_16x16x32_bf16(a1[2 * c][0], bz0, b1a, 0, 0, 0);
                f32x4 h1 = __builtin_amdgcn_mfma_f32_16x16x32_bf16(a1[2 * c + 1][0], bz0, b1b, 0, 0, 0);
                h0 = __builtin_amdgcn_mfma_f32_16x16x32_bf16(a1[2 * c][1], bz1, h0, 0, 0, 0);
                h1 = __builtin_amdgcn_mfma_f32_16x16x32_bf16(a1[2 * c + 1][1], bz1, h1, 0, 0, 0);
                bh[c].u[0] = cvt_pk(fmaxf(h0[0], 0.f), fmaxf(h0[1], 0.f));
                bh[c].u[1] = cvt_pk(fmaxf(h0[2], 0.f), fmaxf(h0[3], 0.f));
                bh[c].u[2] = cvt_pk(fmaxf(h1[0], 0.f), fmaxf(h1[1], 0.f));
                bh[c].u[3] = cvt_pk(fmaxf(h1[2], 0.f), fmaxf(h1[3], 0.f));
            }

            // ---- layer2: 4 tiles x 4 chunks (bias via C-init) ----
            f32x4 cc[4];
#pragma unroll
            for (int tt = 0; tt < 4; ++tt)
                cc[tt] = __builtin_amdgcn_mfma_f32_16x16x32_bf16(a2[tt][0], bh[0].v, b2i[tt], 0, 0, 0);
#pragma unroll
            for (int c = 1; c < 4; ++c)
#pragma unroll
                for (int tt = 0; tt < 4; ++tt)
                    cc[tt] = __builtin_amdgcn_mfma_f32_16x16x32_bf16(a2[tt][c], bh[c].v, cc[tt], 0, 0, 0);

            // ---- tanh + contraction ----
            float pt[4];
#pragma unroll
            for (int tt = 0; tt < 4; ++tt) {
                f32x2 s2 = {0.f, 0.f};
#pragma unroll
                for (int r2 = 0; r2 < 2; ++r2) {
                    f32x2 x = { cc[tt][2 * r2], cc[tt][2 * r2 + 1] };
                    f32x2 a = x * 2.8853900817779268f;
                    f32x2 e = { __builtin_amdgcn_exp2f(a.x),
                                __builtin_amdgcn_exp2f(a.y) };
                    e = e + 1.0f;
                    f32x2 rr = { __builtin_amdgcn_rcpf(e.x),
                                 __builtin_amdgcn_rcpf(e.y) };
                    f32x2 th = (-2.0f) * rr + 1.0f;
                    f32x2 d2 = { dd[2 * r2], dd[2 * r2 + 1] };
                    s2 = th * d2 + s2;
                }
                pt[tt] = s2.x + s2.y;
            }
#pragma unroll
            for (int tt = 0; tt < 4; ++tt)
                pt[tt] += xor16(pt[tt]);   // sum over g0

            // ---- RK4 update (all lanes track; (lane&16)==0 write packed) ----
            float zw[4];
#pragma unroll
            for (int tt = 0; tt < 4; ++tt) {
                const float k = pt[tt];
                float zst;
                if (st == 0)      { zs[tt] = k;                    zst = fmaf(hs_half, k, zreg[tt]); }
                else if (st == 1) { zs[tt] = fmaf(2.f, k, zs[tt]); zst = fmaf(hs_half, k, zreg[tt]); }
                else if (st == 2) { zs[tt] = fmaf(2.f, k, zs[tt]); zst = fmaf(hs, k, zreg[tt]); }
                else              { zs[tt] += k;                   zst = fmaf(hs_sixth, zs[tt], zreg[tt]);
                                    zreg[tt] = zst; }
                zw[tt] = zst;
            }
            if (!(lane & 16)) {
                int2 wd;
                wd.x = (int)cvt_pk(zw[0], zw[1]);
                wd.y = (int)cvt_pk(zw[2], zw[3]);
                *(int2*)(rb ? zwp0 : zwp1) = wd;   // write buffer rb^1
            }
        }
    }

    // ---------------- readout: sigmoid(z @ lin_W + lin_b) --------------------
    float p = 0.f;
#pragma unroll
    for (int tt = 0; tt < 4; ++tt) p += zreg[tt] * linW[8 * wv + 2 * tt + hi];
    p += __shfl_xor(p, 32);
    if (lane < 16) pred[wv][col] = p;
    __syncthreads();
    if (tid < 16) {
        float a = linb[0];
#pragma unroll
        for (int w = 0; w < 8; ++w) a += pred[w][tid];
        out[s0 + tid] = 1.0f / (1.0f + __expf(-a));
    }
}

extern "C" void kernel_launch(void* const* d_in, const int* in_sizes, int n_in,
                              void* d_out, int out_size, void* d_ws, size_t ws_size,
                              hipStream_t stream) {
    (void)in_sizes; (void)n_in; (void)d_ws; (void)ws_size; (void)out_size;
    const float* times = (const float*)d_in[0];
    const float* ca    = (const float*)d_in[1];
    const float* cb    = (const float*)d_in[2];
    const float* c2c   = (const float*)d_in[3];
    const float* c3d   = (const float*)d_in[4];
    const float* initW = (const float*)d_in[5];
    const float* initb = (const float*)d_in[6];
    const float* W1    = (const float*)d_in[7];
    const float* b1    = (const float*)d_in[8];
    const float* W2    = (const float*)d_in[9];
    const float* b2    = (const float*)d_in[10];
    const float* linW  = (const float*)d_in[11];
    const float* linb  = (const float*)d_in[12];
    cde_kernel<<<32, 512, 0, stream>>>(times, ca, cb, c2c, c3d, initW, initb,
                                       W1, b1, W2, b2, linW, linb, (float*)d_out);
}